// Round 3
// baseline (1267.248 us; speedup 1.0000x reference)
//
#include <hip/hip_runtime.h>
#include <cstddef>

#define BB 4
#define SS 2048
#define DMOD 32
#define AEL (BB*SS*DMOD)          // 262144 floats per projection array
#define WS_PROJ 16                 // floats offset: [0..3]=c*invsqrt8, [4]=cb
#define WS_PART (16 + 8*AEL)
#define TINY 1e-30f
#define JSUB 32
#define LDST 33                    // padded LDS row stride (floats)

__device__ __forceinline__ float fexp2(float x) {
#if defined(__has_builtin)
#if __has_builtin(__builtin_amdgcn_exp2f)
    return __builtin_amdgcn_exp2f(x);
#else
    return exp2f(x);
#endif
#else
    return exp2f(x);
#endif
}

// ---------- kernel 0: collapse conv stack to c[4], cb ----------
__global__ void k0_cw(const float* __restrict__ f1w, const float* __restrict__ f1b,
                      const float* __restrict__ f2w, const float* __restrict__ f2b,
                      const float* __restrict__ f3w, const float* __restrict__ f3b,
                      float* __restrict__ wsf) {
    if (threadIdx.x == 0 && blockIdx.x == 0) {
        for (int h = 0; h < 4; h++) {
            float s = 0.f;
            for (int a = 0; a < 4; a++) {
                float t = 0.f;
                for (int bb = 0; bb < 8; bb++) t += f2w[a*8+bb] * f1w[bb*4+h];
                s += f3w[a] * t;
            }
            wsf[h] = s * 0.35355339059327373f;   // fold 1/sqrt(8)
        }
        float cb = f3b[0];
        for (int a = 0; a < 4; a++) {
            float t = f2b[a];
            for (int bb = 0; bb < 8; bb++) t += f2w[a*8+bb] * f1b[bb];
            cb += f3w[a] * t;
        }
        wsf[4] = cb;
    }
}

// ---------- kernel 1: all 8 projections ----------
// mats: 0 q_o (scaled by c_h/sqrt8), 1 k_o, 2 q_p (log2e/sqrt8), 3 k_p, 4 v_p,
//       5 q_n (log2e/sqrt8), 6 k_n, 7 v_n
__global__ __launch_bounds__(256) void k1_proj(
    const float* __restrict__ feat,
    const float* __restrict__ qw, const float* __restrict__ qb,
    const float* __restrict__ kw, const float* __restrict__ kb,
    const float* __restrict__ paw, const float* __restrict__ pab,
    const float* __restrict__ naw, const float* __restrict__ nab,
    float* __restrict__ wsf) {
    int g = blockIdx.x * 256 + threadIdx.x;     // 524288 threads
    int d4  = g & 7;
    int mat = (g >> 3) & 7;
    int row = g >> 6;                            // 0..8191 (uniform per wave)
    const float* W; const float* Bv; float sc = 1.f;
    switch (mat) {
        case 0: W = qw;        Bv = qb;       break;
        case 1: W = kw;        Bv = kb;       break;
        case 2: W = paw;       Bv = pab;      sc = 0.5101370246954918f; break;
        case 3: W = paw+1024;  Bv = pab+32;   break;
        case 4: W = paw+2048;  Bv = pab+64;   break;
        case 5: W = naw;       Bv = nab;      sc = 0.5101370246954918f; break;
        case 6: W = naw+1024;  Bv = nab+32;   break;
        default:W = naw+2048;  Bv = nab+64;   break;
    }
    const float* fr = feat + row * DMOD;
    int o0 = d4 * 4;
    float acc[4];
    #pragma unroll
    for (int i = 0; i < 4; i++) acc[i] = Bv[o0+i];
    #pragma unroll
    for (int d = 0; d < DMOD; d++) {
        float fv = fr[d];
        #pragma unroll
        for (int i = 0; i < 4; i++) acc[i] += fv * W[(o0+i)*DMOD + d];
    }
    if (mat == 0) {
        #pragma unroll
        for (int i = 0; i < 4; i++) acc[i] *= wsf[(o0+i) >> 3];  // c_h/sqrt8
    } else {
        #pragma unroll
        for (int i = 0; i < 4; i++) acc[i] *= sc;
    }
    float4 r = make_float4(acc[0], acc[1], acc[2], acc[3]);
    *(float4*)(wsf + WS_PROJ + (size_t)mat*AEL + (size_t)row*DMOD + o0) = r;
}

// ---------- kernel 2: fused mask + dual masked attention (split-K) ----------
__global__ __launch_bounds__(256, 4) void k2_attn(
    const float* __restrict__ dmask, const float* __restrict__ wsf,
    float* __restrict__ part, int CJ) {
    __shared__ float dmt[256 * LDST];           // 33.8 KB
    int tid = threadIdx.x;
    int jc = blockIdx.x, rt = blockIdx.y, b = blockIdx.z;
    int row  = rt * 256 + tid;          // row within batch
    int grow = b * SS + row;            // global row 0..8191

    float qo[32], qp[32], qn[32];
    {
        const float* QO = wsf + WS_PROJ + 0*(size_t)AEL + (size_t)grow*DMOD;
        const float* QP = wsf + WS_PROJ + 2*(size_t)AEL + (size_t)grow*DMOD;
        const float* QN = wsf + WS_PROJ + 5*(size_t)AEL + (size_t)grow*DMOD;
        #pragma unroll
        for (int i = 0; i < 8; i++) {
            float4 a = *(const float4*)(QO + 4*i);
            qo[4*i] = a.x; qo[4*i+1] = a.y; qo[4*i+2] = a.z; qo[4*i+3] = a.w;
            float4 c = *(const float4*)(QP + 4*i);
            qp[4*i] = c.x; qp[4*i+1] = c.y; qp[4*i+2] = c.z; qp[4*i+3] = c.w;
            float4 d = *(const float4*)(QN + 4*i);
            qn[4*i] = d.x; qn[4*i+1] = d.y; qn[4*i+2] = d.z; qn[4*i+3] = d.w;
        }
    }
    const float cbv = wsf[4];
    const float* KO = wsf + WS_PROJ + 1*(size_t)AEL + (size_t)b*SS*DMOD;
    const float* KP = wsf + WS_PROJ + 3*(size_t)AEL + (size_t)b*SS*DMOD;
    const float* VP = wsf + WS_PROJ + 4*(size_t)AEL + (size_t)b*SS*DMOD;
    const float* KN = wsf + WS_PROJ + 6*(size_t)AEL + (size_t)b*SS*DMOD;
    const float* VN = wsf + WS_PROJ + 7*(size_t)AEL + (size_t)b*SS*DMOD;

    float lp[4] = {0,0,0,0}, ln[4] = {0,0,0,0};
    float ap[32], an[32];
    #pragma unroll
    for (int i = 0; i < 32; i++) { ap[i] = 0.f; an[i] = 0.f; }

    int j0 = jc * CJ;
    for (int js = 0; js < CJ; js += JSUB) {
        int jbase = j0 + js;
        __syncthreads();
        // cooperative coalesced staging of 256 rows x JSUB mask values
        #pragma unroll
        for (int k = 0; k < 8; k++) {
            int flat = k * 1024 + tid * 4;       // 0..8191
            int r  = flat >> 5;                  // row-local 0..255
            int jj = flat & 31;                  // j-local, multiple of 4
            float4 v = *(const float4*)(dmask + (size_t)(b*SS + rt*256 + r)*SS + jbase + jj);
            float* dst = dmt + r * LDST + jj;
            dst[0] = v.x; dst[1] = v.y; dst[2] = v.z; dst[3] = v.w;
        }
        __syncthreads();
        for (int j4 = 0; j4 < JSUB; j4 += 4) {
            #pragma unroll
            for (int jj = 0; jj < 4; jj++) {
                float dmv = dmt[tid * LDST + j4 + jj];
                int kbv = (jbase + j4 + jj) * DMOD;
                // fused score (outer QK combined with conv weights): 4 ILP chains
                float fa = 0.f, fb = 0.f, fc = 0.f, fd = 0.f;
                #pragma unroll
                for (int d = 0; d < 8; d++) {
                    fa += qo[d]      * KO[kbv + d];
                    fb += qo[8 + d]  * KO[kbv + 8 + d];
                    fc += qo[16 + d] * KO[kbv + 16 + d];
                    fd += qo[24 + d] * KO[kbv + 24 + d];
                }
                float fused = cbv + ((fa + fb) + (fc + fd));
                bool act = (dmv != 0.0f);
                bool pA = act && (fused > 0.0f);
                bool nA = act && !(fused > 0.0f);
                #pragma unroll
                for (int h = 0; h < 4; h++) {
                    float sp = 0.f, sn = 0.f;
                    #pragma unroll
                    for (int e = 0; e < 8; e++) {
                        sp += qp[h*8+e] * KP[kbv + h*8 + e];
                        sn += qn[h*8+e] * KN[kbv + h*8 + e];
                    }
                    float wp = pA ? fexp2(sp) : TINY;
                    float wn = nA ? fexp2(sn) : TINY;
                    lp[h] += wp; ln[h] += wn;
                    #pragma unroll
                    for (int e = 0; e < 8; e++) {
                        ap[h*8+e] += wp * VP[kbv + h*8 + e];
                        an[h*8+e] += wn * VN[kbv + h*8 + e];
                    }
                }
            }
        }
    }
    // partial layout: [chunk][72][8192]; k: 0..3 lp, 4..7 ln, 8..39 ap, 40..71 an
    float* pb = part + (size_t)(jc * 72) * 8192 + grow;
    #pragma unroll
    for (int h = 0; h < 4; h++) {
        pb[(size_t)h * 8192]     = lp[h];
        pb[(size_t)(4+h) * 8192] = ln[h];
    }
    #pragma unroll
    for (int i = 0; i < 32; i++) {
        pb[(size_t)(8+i)  * 8192] = ap[i];
        pb[(size_t)(40+i) * 8192] = an[i];
    }
}

// ---------- kernel 3a: parallel reduction of split-K partials into chunk 0 ----------
__global__ __launch_bounds__(256) void k3a_red(float* __restrict__ part, int NCH) {
    int e4 = blockIdx.x * 256 + threadIdx.x;    // 147456 float4 slots
    size_t e = (size_t)e4 * 4;                  // < 72*8192
    float4 s = *(const float4*)(part + e);
    for (int c = 1; c < NCH; c++) {
        const float4 v = *(const float4*)(part + (size_t)c * 72 * 8192 + e);
        s.x += v.x; s.y += v.y; s.z += v.z; s.w += v.w;
    }
    *(float4*)(part + e) = s;
}

// ---------- kernel 3b: normalize + out-proj + gate ----------
__global__ __launch_bounds__(128) void k3_fin(
    const float* __restrict__ part,
    const float* __restrict__ paw, const float* __restrict__ pab,
    const float* __restrict__ naw, const float* __restrict__ nab,
    const float* __restrict__ vpw, const float* __restrict__ vpb,
    const float* __restrict__ vnw, const float* __restrict__ vnb,
    const float* __restrict__ gpw, const float* __restrict__ gpb,
    float* __restrict__ out) {
    int row = blockIdx.x * 128 + threadIdx.x;   // 0..8191
    float s[72];
    #pragma unroll
    for (int k = 0; k < 72; k++) s[k] = part[(size_t)k * 8192 + row];
    float Pp[32], Pn[32];
    #pragma unroll
    for (int h = 0; h < 4; h++) {
        float il  = 1.0f / s[h];
        float iln = 1.0f / s[4 + h];
        #pragma unroll
        for (int e = 0; e < 8; e++) {
            Pp[h*8+e] = s[8  + h*8 + e] * il;
            Pn[h*8+e] = s[40 + h*8 + e] * iln;
        }
    }
    const float* pw3 = paw + 3*1024; const float* pb3 = pab + 3*32;
    const float* nw3 = naw + 3*1024; const float* nb3 = nab + 3*32;
    float p[32], n[32];
    #pragma unroll
    for (int o = 0; o < 32; o++) {
        float a = pb3[o], c = nb3[o];
        #pragma unroll
        for (int d = 0; d < 32; d++) {
            a += Pp[d] * pw3[o*32 + d];
            c += Pn[d] * nw3[o*32 + d];
        }
        p[o] = a; n[o] = c;
    }
    #pragma unroll
    for (int o = 0; o < 32; o++) {
        float vp = vpb[o], vn = vnb[o], ep = gpb[o], en = gpb[o];
        #pragma unroll
        for (int d = 0; d < 32; d++) {
            vp += p[d] * vpw[o*32 + d];
            vn += n[d] * vnw[o*32 + d];
            ep += p[d] * gpw[o*32 + d];
            en += n[d] * gpw[o*32 + d];
        }
        float g = 1.0f / (1.0f + __expf(en - ep));
        out[(size_t)row * 32 + o] = vp * g + vn * (1.0f - g);
    }
}

extern "C" void kernel_launch(void* const* d_in, const int* in_sizes, int n_in,
                              void* d_out, int out_size, void* d_ws, size_t ws_size,
                              hipStream_t stream) {
    const float* feat  = (const float*)d_in[0];
    const float* dmask = (const float*)d_in[1];
    const float* qw  = (const float*)d_in[2];  const float* qb  = (const float*)d_in[3];
    const float* kw  = (const float*)d_in[4];  const float* kb  = (const float*)d_in[5];
    const float* f1w = (const float*)d_in[6];  const float* f1b = (const float*)d_in[7];
    const float* f2w = (const float*)d_in[8];  const float* f2b = (const float*)d_in[9];
    const float* f3w = (const float*)d_in[10]; const float* f3b = (const float*)d_in[11];
    const float* paw = (const float*)d_in[12]; const float* pab = (const float*)d_in[13];
    const float* naw = (const float*)d_in[14]; const float* nab = (const float*)d_in[15];
    const float* vpw = (const float*)d_in[16]; const float* vpb = (const float*)d_in[17];
    const float* vnw = (const float*)d_in[18]; const float* vnb = (const float*)d_in[19];
    const float* gpw = (const float*)d_in[20]; const float* gpb = (const float*)d_in[21];
    float* wsf = (float*)d_ws;
    float* out = (float*)d_out;

    // pick split-K chunk count that fits ws (each chunk: 72*8192 floats)
    size_t avail = ws_size / 4;
    int nch = 1;
    if (avail > (size_t)WS_PART) {
        size_t per = (size_t)72 * 8192;
        size_t m = (avail - WS_PART) / per;
        nch = (m >= 32) ? 32 : (m >= 16) ? 16 : (m >= 8) ? 8 : (m >= 4) ? 4 : (m >= 2) ? 2 : 1;
    }
    int cj = SS / nch;
    float* part = wsf + WS_PART;

    hipLaunchKernelGGL(k0_cw, dim3(1), dim3(64), 0, stream,
                       f1w, f1b, f2w, f2b, f3w, f3b, wsf);
    hipLaunchKernelGGL(k1_proj, dim3(2048), dim3(256), 0, stream,
                       feat, qw, qb, kw, kb, paw, pab, naw, nab, wsf);
    hipLaunchKernelGGL(k2_attn, dim3(nch, 8, BB), dim3(256), 0, stream,
                       dmask, wsf, part, cj);
    if (nch > 1)
        hipLaunchKernelGGL(k3a_red, dim3(576), dim3(256), 0, stream, part, nch);
    hipLaunchKernelGGL(k3_fin, dim3(64), dim3(128), 0, stream,
                       part, paw, pab, naw, nab, vpw, vpb, vnw, vnb, gpw, gpb,
                       out);
}

// Round 4
// 444.928 us; speedup vs baseline: 2.8482x; 2.8482x over previous
//
#include <hip/hip_runtime.h>
#include <cstddef>

#define BB 4
#define SS 2048
#define DMOD 32
#define AEL (BB*SS*DMOD)            // 262144 floats per projection array
#define WS_PROJ 16                  // [0..3]=c*invsqrt8, [4]=cb
#define MB0 (WS_PROJ + 8*AEL)       // 2097168: pmask (u64, 262144) then nmask
#define MWORDS (BB*32*SS)           // 262144 u64 per mask
#define PART0 (MB0 + 4*MWORDS)      // 3145744 floats (each u64 = 2 floats)
#define PSLOT (36*8192)             // floats per (pn, chunk) partial slot
#define TINY 1e-30f

__device__ __forceinline__ float fexp2(float x) { return exp2f(x); }

// ---------- kernel 0: collapse conv stack to c[4], cb ----------
__global__ void k0_cw(const float* __restrict__ f1w, const float* __restrict__ f1b,
                      const float* __restrict__ f2w, const float* __restrict__ f2b,
                      const float* __restrict__ f3w, const float* __restrict__ f3b,
                      float* __restrict__ wsf) {
    if (threadIdx.x == 0 && blockIdx.x == 0) {
        for (int h = 0; h < 4; h++) {
            float s = 0.f;
            for (int a = 0; a < 4; a++) {
                float t = 0.f;
                for (int bb = 0; bb < 8; bb++) t += f2w[a*8+bb] * f1w[bb*4+h];
                s += f3w[a] * t;
            }
            wsf[h] = s * 0.35355339059327373f;   // fold 1/sqrt(8)
        }
        float cb = f3b[0];
        for (int a = 0; a < 4; a++) {
            float t = f2b[a];
            for (int bb = 0; bb < 8; bb++) t += f2w[a*8+bb] * f1b[bb];
            cb += f3w[a] * t;
        }
        wsf[4] = cb;
    }
}

// ---------- kernel 1: all 8 projections ----------
// mats: 0 q_o (scaled c_h/sqrt8), 1 k_o, 2 q_p (log2e/sqrt8), 3 k_p, 4 v_p,
//       5 q_n (log2e/sqrt8), 6 k_n, 7 v_n
__global__ __launch_bounds__(256) void k1_proj(
    const float* __restrict__ feat,
    const float* __restrict__ qw, const float* __restrict__ qb,
    const float* __restrict__ kw, const float* __restrict__ kb,
    const float* __restrict__ paw, const float* __restrict__ pab,
    const float* __restrict__ naw, const float* __restrict__ nab,
    float* __restrict__ wsf) {
    int g = blockIdx.x * 256 + threadIdx.x;
    int d4  = g & 7;
    int mat = (g >> 3) & 7;
    int row = g >> 6;
    const float* W; const float* Bv; float sc = 1.f;
    switch (mat) {
        case 0: W = qw;        Bv = qb;       break;
        case 1: W = kw;        Bv = kb;       break;
        case 2: W = paw;       Bv = pab;      sc = 0.5101370246954918f; break;
        case 3: W = paw+1024;  Bv = pab+32;   break;
        case 4: W = paw+2048;  Bv = pab+64;   break;
        case 5: W = naw;       Bv = nab;      sc = 0.5101370246954918f; break;
        case 6: W = naw+1024;  Bv = nab+32;   break;
        default:W = naw+2048;  Bv = nab+64;   break;
    }
    const float* fr = feat + row * DMOD;
    int o0 = d4 * 4;
    float acc[4];
    #pragma unroll
    for (int i = 0; i < 4; i++) acc[i] = Bv[o0+i];
    #pragma unroll
    for (int d = 0; d < DMOD; d++) {
        float fv = fr[d];
        #pragma unroll
        for (int i = 0; i < 4; i++) acc[i] += fv * W[(o0+i)*DMOD + d];
    }
    if (mat == 0) {
        #pragma unroll
        for (int i = 0; i < 4; i++) acc[i] *= wsf[(o0+i) >> 3];
    } else {
        #pragma unroll
        for (int i = 0; i < 4; i++) acc[i] *= sc;
    }
    float4 r = make_float4(acc[0], acc[1], acc[2], acc[3]);
    *(float4*)(wsf + WS_PROJ + (size_t)mat*AEL + (size_t)row*DMOD + o0) = r;
}

// ---------- kernel A: fused-score sign bits -> packed p/n masks ----------
// grid (jt=8, rt=16, b=4), block 256 = 4 waves x 64 lanes (lane = j offset)
__global__ __launch_bounds__(256) void kA_mask(
    const float* __restrict__ dmask, float* __restrict__ wsf) {
    int tid = threadIdx.x;
    int w = tid >> 6, lane = tid & 63;
    int jt = blockIdx.x, rt = blockIdx.y, b = blockIdx.z;
    int jg = jt * 256 + w * 64 + lane;          // batch-local j
    const float cbv = wsf[4];
    const float* KOb = wsf + WS_PROJ + 1*(size_t)AEL + ((size_t)b*SS + jg) * DMOD;
    float ko[32];
    #pragma unroll
    for (int i = 0; i < 8; i++) {
        float4 v = *(const float4*)(KOb + 4*i);
        ko[4*i] = v.x; ko[4*i+1] = v.y; ko[4*i+2] = v.z; ko[4*i+3] = v.w;
    }
    const float* QOb = wsf + WS_PROJ + 0*(size_t)AEL + (size_t)b*SS*DMOD;
    unsigned long long* pm = (unsigned long long*)(wsf + MB0);
    unsigned long long* nm = pm + MWORDS;
    int j64 = jt * 4 + w;
    size_t mbase = ((size_t)b * 32 + j64) * SS;
    #pragma unroll 2
    for (int r = 0; r < 128; r++) {
        int row = rt * 128 + r;
        const float* qr = QOb + (size_t)row * DMOD;
        float fa = 0.f, fb = 0.f, fc = 0.f, fd = 0.f;
        #pragma unroll
        for (int d = 0; d < 8; d++) {
            fa += qr[d]      * ko[d];
            fb += qr[8 + d]  * ko[8 + d];
            fc += qr[16 + d] * ko[16 + d];
            fd += qr[24 + d] * ko[24 + d];
        }
        float fused = cbv + ((fa + fb) + (fc + fd));
        float dm = dmask[((size_t)b * SS + row) * SS + jg];
        bool act = (dm != 0.0f);
        unsigned long long bp = __ballot(act && (fused > 0.0f));
        unsigned long long bn = __ballot(act && !(fused > 0.0f));
        if (lane == 0) {
            pm[mbase + row] = bp;
            nm[mbase + row] = bn;
        }
    }
}

// ---------- kernel B: masked attention (p or n), split-K ----------
// grid (jc=NCH, rt=16, z=8: b=z>>1, pn=z&1), block 256 = 128 rows x 2 head-pairs
__global__ __launch_bounds__(256) void kB_attn(
    const float* __restrict__ wsf_c, float* __restrict__ wsf, int CJ) {
    int tid = threadIdx.x;
    int rr = tid >> 1, hp = tid & 1;
    int jc = blockIdx.x, rt = blockIdx.y;
    int b = blockIdx.z >> 1, pn = blockIdx.z & 1;
    int row = rt * 128 + rr;
    size_t grow = (size_t)b * SS + row;

    int qm = pn ? 5 : 2, km = pn ? 6 : 3, vm = pn ? 7 : 4;
    const float* Qb = wsf_c + WS_PROJ + (size_t)qm*AEL + grow*DMOD + hp*16;
    const float* Kb = wsf_c + WS_PROJ + (size_t)km*AEL + (size_t)b*SS*DMOD;
    const float* Vb = wsf_c + WS_PROJ + (size_t)vm*AEL + (size_t)b*SS*DMOD;
    const unsigned long long* msk =
        (const unsigned long long*)(wsf_c + MB0) + (size_t)pn * MWORDS;

    float ql[16];
    #pragma unroll
    for (int i = 0; i < 4; i++) {
        float4 v = *(const float4*)(Qb + 4*i);
        ql[4*i] = v.x; ql[4*i+1] = v.y; ql[4*i+2] = v.z; ql[4*i+3] = v.w;
    }
    float a[16];
    #pragma unroll
    for (int i = 0; i < 16; i++) a[i] = 0.f;
    float l0 = 0.f, l1 = 0.f;

    int jA0 = jc * CJ;
    for (int j0 = 0; j0 < CJ; j0 += 64) {
        int jA = jA0 + j0;
        unsigned long long mw = msk[((size_t)b * 32 + (jA >> 6)) * SS + row];
        #pragma unroll 4
        for (int jj = 0; jj < 64; jj++) {
            const float* kp = Kb + ((size_t)(jA + jj) << 5) + (hp << 4);
            const float* vp = Vb + ((size_t)(jA + jj) << 5) + (hp << 4);
            float kk[16], vv[16];
            #pragma unroll
            for (int i = 0; i < 4; i++) {
                *(float4*)(kk + 4*i) = *(const float4*)(kp + 4*i);
                *(float4*)(vv + 4*i) = *(const float4*)(vp + 4*i);
            }
            float s0 = 0.f, s1 = 0.f;
            #pragma unroll
            for (int e = 0; e < 8; e++) {
                s0 += ql[e]     * kk[e];
                s1 += ql[8 + e] * kk[8 + e];
            }
            bool bit = ((unsigned)(mw >> jj) & 1u) != 0u;
            float w0 = bit ? fexp2(s0) : TINY;
            float w1 = bit ? fexp2(s1) : TINY;
            l0 += w0; l1 += w1;
            #pragma unroll
            for (int e = 0; e < 8; e++) {
                a[e]     += w0 * vv[e];
                a[8 + e] += w1 * vv[8 + e];
            }
        }
    }
    // partial slot: [pn*NCH + jc][36][8192]; k = hp*18 + {l0, l1, a[0..15]}
    float* pb = wsf + PART0 + (size_t)(pn * gridDim.x + jc) * PSLOT + grow;
    int k0i = hp * 18;
    pb[(size_t)(k0i + 0) * 8192] = l0;
    pb[(size_t)(k0i + 1) * 8192] = l1;
    #pragma unroll
    for (int e = 0; e < 16; e++)
        pb[(size_t)(k0i + 2 + e) * 8192] = a[e];
}

// ---------- kernel 3a: reduce split-K partials into chunk 0 (per pn) ----------
__global__ __launch_bounds__(256) void k3a_red(float* __restrict__ part, int NCH) {
    int idx = blockIdx.x * 256 + threadIdx.x;   // 147456 float4 slots (2*36*8192/4)
    size_t e = (size_t)idx * 4;
    int pn = (int)(e / PSLOT);
    size_t off = e - (size_t)pn * PSLOT;
    float* base = part + (size_t)pn * NCH * PSLOT + off;
    float4 s = *(const float4*)base;
    for (int c = 1; c < NCH; c++) {
        float4 v = *(const float4*)(base + (size_t)c * PSLOT);
        s.x += v.x; s.y += v.y; s.z += v.z; s.w += v.w;
    }
    *(float4*)base = s;
}

// ---------- kernel 3b: normalize + out-proj + gate ----------
__global__ __launch_bounds__(128) void k3_fin(
    const float* __restrict__ part, int NCH,
    const float* __restrict__ paw, const float* __restrict__ pab,
    const float* __restrict__ naw, const float* __restrict__ nab,
    const float* __restrict__ vpw, const float* __restrict__ vpb,
    const float* __restrict__ vnw, const float* __restrict__ vnb,
    const float* __restrict__ gpw, const float* __restrict__ gpb,
    float* __restrict__ out) {
    int row = blockIdx.x * 128 + threadIdx.x;   // 0..8191
    const float* sp_ = part + row;                       // pn=0, chunk 0
    const float* sn_ = part + (size_t)NCH * PSLOT + row; // pn=1, chunk 0
    float Pp[32], Pn[32];
    #pragma unroll
    for (int hp = 0; hp < 2; hp++) {
        int k0i = hp * 18;
        float pl0 = sp_[(size_t)(k0i+0)*8192], pl1 = sp_[(size_t)(k0i+1)*8192];
        float nl0 = sn_[(size_t)(k0i+0)*8192], nl1 = sn_[(size_t)(k0i+1)*8192];
        float ip0 = 1.0f/pl0, ip1 = 1.0f/pl1, in0 = 1.0f/nl0, in1 = 1.0f/nl1;
        #pragma unroll
        for (int e = 0; e < 8; e++) {
            Pp[hp*16 + e]     = sp_[(size_t)(k0i+2+e)*8192] * ip0;
            Pp[hp*16 + 8 + e] = sp_[(size_t)(k0i+10+e)*8192] * ip1;
            Pn[hp*16 + e]     = sn_[(size_t)(k0i+2+e)*8192] * in0;
            Pn[hp*16 + 8 + e] = sn_[(size_t)(k0i+10+e)*8192] * in1;
        }
    }
    const float* pw3 = paw + 3*1024; const float* pb3 = pab + 3*32;
    const float* nw3 = naw + 3*1024; const float* nb3 = nab + 3*32;
    float p[32], n[32];
    #pragma unroll
    for (int o = 0; o < 32; o++) {
        float av = pb3[o], cv = nb3[o];
        #pragma unroll
        for (int d = 0; d < 32; d++) {
            av += Pp[d] * pw3[o*32 + d];
            cv += Pn[d] * nw3[o*32 + d];
        }
        p[o] = av; n[o] = cv;
    }
    #pragma unroll
    for (int o = 0; o < 32; o++) {
        float vp = vpb[o], vn = vnb[o], ep = gpb[o], en = gpb[o];
        #pragma unroll
        for (int d = 0; d < 32; d++) {
            vp += p[d] * vpw[o*32 + d];
            vn += n[d] * vnw[o*32 + d];
            ep += p[d] * gpw[o*32 + d];
            en += n[d] * gpw[o*32 + d];
        }
        float g = 1.0f / (1.0f + __expf(en - ep));
        out[(size_t)row * 32 + o] = vp * g + vn * (1.0f - g);
    }
}

extern "C" void kernel_launch(void* const* d_in, const int* in_sizes, int n_in,
                              void* d_out, int out_size, void* d_ws, size_t ws_size,
                              hipStream_t stream) {
    const float* feat  = (const float*)d_in[0];
    const float* dmask = (const float*)d_in[1];
    const float* qw  = (const float*)d_in[2];  const float* qb  = (const float*)d_in[3];
    const float* kw  = (const float*)d_in[4];  const float* kb  = (const float*)d_in[5];
    const float* f1w = (const float*)d_in[6];  const float* f1b = (const float*)d_in[7];
    const float* f2w = (const float*)d_in[8];  const float* f2b = (const float*)d_in[9];
    const float* f3w = (const float*)d_in[10]; const float* f3b = (const float*)d_in[11];
    const float* paw = (const float*)d_in[12]; const float* pab = (const float*)d_in[13];
    const float* naw = (const float*)d_in[14]; const float* nab = (const float*)d_in[15];
    const float* vpw = (const float*)d_in[16]; const float* vpb = (const float*)d_in[17];
    const float* vnw = (const float*)d_in[18]; const float* vnb = (const float*)d_in[19];
    const float* gpw = (const float*)d_in[20]; const float* gpb = (const float*)d_in[21];
    float* wsf = (float*)d_ws;
    float* out = (float*)d_out;

    // pick split-K chunk count that fits ws (per chunk: 2 pn x 36*8192 floats)
    size_t avail = ws_size / 4;
    int nch = 1;
    if (avail > (size_t)PART0) {
        size_t per = (size_t)2 * PSLOT;
        size_t m = (avail - PART0) / per;
        nch = (m >= 16) ? 16 : (m >= 8) ? 8 : (m >= 4) ? 4 : (m >= 2) ? 2 : 1;
    }
    int cj = SS / nch;
    float* part = wsf + PART0;

    hipLaunchKernelGGL(k0_cw, dim3(1), dim3(64), 0, stream,
                       f1w, f1b, f2w, f2b, f3w, f3b, wsf);
    hipLaunchKernelGGL(k1_proj, dim3(2048), dim3(256), 0, stream,
                       feat, qw, qb, kw, kb, paw, pab, naw, nab, wsf);
    hipLaunchKernelGGL(kA_mask, dim3(8, 16, BB), dim3(256), 0, stream,
                       dmask, wsf);
    hipLaunchKernelGGL(kB_attn, dim3(nch, 16, BB*2), dim3(256), 0, stream,
                       wsf, wsf, cj);
    if (nch > 1)
        hipLaunchKernelGGL(k3a_red, dim3(576), dim3(256), 0, stream, part, nch);
    hipLaunchKernelGGL(k3_fin, dim3(64), dim3(128), 0, stream,
                       part, nch, paw, pab, naw, nab, vpw, vpb, vnw, vnb, gpw, gpb,
                       out);
}